// Round 4
// baseline (108.105 us; speedup 1.0000x reference)
//
#include <hip/hip_runtime.h>
#include <hip/hip_cooperative_groups.h>
#include <math.h>

namespace cg = cooperative_groups;

#define MARGIN 5.0f
#define NB 384
#define ND 256
#define ND4 (ND / 4)   // 64 float4 per row

// One cooperative kernel: transpose -> sync -> distances+triplet -> sync -> reduce.
__global__ __launch_bounds__(384) void fused_kernel(const float* __restrict__ emb,
                                                    const int* __restrict__ labels,
                                                    float4* __restrict__ embT,    // [ND4][NB]
                                                    float* __restrict__ partial,  // [2*NB]
                                                    float* __restrict__ out) {
    cg::grid_group grid = cg::this_grid();

    const int i = blockIdx.x;
    const int t = threadIdx.x;

    // ---- phase A: build embT[d4][j] = float4(emb[j][4*d4 .. 4*d4+3]) ----
    // g consecutive -> coalesced float4 read of emb; scatter write (393 KB total, cheap).
    {
        const int g = i * 384 + t;
        if (g < ND4 * NB) {
            const int d4 = g & (ND4 - 1);
            const int j  = g >> 6;
            embT[d4 * NB + j] = ((const float4*)emb)[g];
        }
    }
    grid.sync();

    // ---- phase B: block i = anchor i; thread t owns j = t ----
    __shared__ float4 s_ei[ND4];
    __shared__ float  s_row[NB];
    __shared__ int    s_plist[64];
    __shared__ int    s_cnt;
    __shared__ float  s_red[12];

    if (t == 0) s_cnt = 0;
    if (t < ND4) s_ei[t] = ((const float4*)(emb + (size_t)i * ND))[t];
    __syncthreads();

    float acc0 = 0.f, acc1 = 0.f;
    #pragma unroll 8
    for (int d4 = 0; d4 < ND4; ++d4) {
        float4 e = s_ei[d4];                 // LDS broadcast
        float4 v = embT[d4 * NB + t];        // 16B/lane, perfectly coalesced
        float a0 = e.x - v.x, a1 = e.y - v.y, a2 = e.z - v.z, a3 = e.w - v.w;
        acc0 = fmaf(a0, a0, acc0);
        acc1 = fmaf(a1, a1, acc1);
        acc0 = fmaf(a2, a2, acc0);
        acc1 = fmaf(a3, a3, acc1);
    }
    const float r1 = sqrtf(acc0 + acc1);
    s_row[t] = r1;

    const int li  = labels[i];               // uniform
    const int lt  = labels[t];               // coalesced
    const bool neg = (lt != li);
    __syncthreads();

    if (!neg && t != i) {
        int p = atomicAdd(&s_cnt, 1);
        if (p < 64) s_plist[p] = t;
    }
    __syncthreads();

    const int np = (s_cnt < 64) ? s_cnt : 64;
    float sum = 0.f, cnt = 0.f;
    if (neg) {
        for (int p = 0; p < np; ++p) {
            float v = s_row[s_plist[p]] + MARGIN - r1;
            if (v > 0.f)    sum += v;
            if (v > 1e-16f) cnt += 1.f;
        }
    }

    #pragma unroll
    for (int off = 32; off; off >>= 1) {
        sum += __shfl_xor(sum, off, 64);
        cnt += __shfl_xor(cnt, off, 64);
    }
    const int w = t >> 6;
    if ((t & 63) == 0) { s_red[w] = sum; s_red[6 + w] = cnt; }
    __syncthreads();
    if (t == 0) {
        float ts = 0.f, tc = 0.f;
        #pragma unroll
        for (int q = 0; q < 6; ++q) { ts += s_red[q]; tc += s_red[6 + q]; }
        partial[2 * i]     = ts;
        partial[2 * i + 1] = tc;
    }
    grid.sync();

    // ---- phase C: block 0 reduces the 384 partial pairs ----
    if (i == 0) {
        float fs = partial[2 * t];
        float fc = partial[2 * t + 1];
        #pragma unroll
        for (int off = 32; off; off >>= 1) {
            fs += __shfl_xor(fs, off, 64);
            fc += __shfl_xor(fc, off, 64);
        }
        if ((t & 63) == 0) { s_red[w] = fs; s_red[6 + w] = fc; }
        __syncthreads();
        if (t == 0) {
            float ts = 0.f, tc = 0.f;
            #pragma unroll
            for (int q = 0; q < 6; ++q) { ts += s_red[q]; tc += s_red[6 + q]; }
            out[0] = ts / (tc + 1e-16f);
        }
    }
}

extern "C" void kernel_launch(void* const* d_in, const int* in_sizes, int n_in,
                              void* d_out, int out_size, void* d_ws, size_t ws_size,
                              hipStream_t stream) {
    const float* emb    = (const float*)d_in[0];
    const int*   labels = (const int*)d_in[1];
    float*       out    = (float*)d_out;

    float4* embT    = (float4*)d_ws;                                        // 64*384*16 = 393216 B
    float*  partial = (float*)((char*)d_ws + (size_t)ND4 * NB * sizeof(float4));

    void* args[] = { (void*)&emb, (void*)&labels, (void*)&embT,
                     (void*)&partial, (void*)&out };
    hipLaunchCooperativeKernel((const void*)fused_kernel, dim3(NB), dim3(NB),
                               args, 0, stream);
}

// Round 5
// 38.390 us; speedup vs baseline: 2.8160x; 2.8160x over previous
//
#include <hip/hip_runtime.h>
#include <math.h>

#define MARGIN 5.0f
#define NB 384
#define ND 256
#define MAGIC_A 0x51B7A5E1u
#define MAGIC_B 0xC3D2E1F0u

// One plain kernel: per-anchor block computes distances + triplet partial,
// publishes {sum,cnt} with magic-tagged release stores; block 0 spin-collects,
// reduces, writes the scalar, and resets the slots (self-cleaning scratch).
__global__ __launch_bounds__(384) void fused_kernel(const float* __restrict__ emb,
                                                    const int* __restrict__ labels,
                                                    unsigned long long* __restrict__ slotA,
                                                    unsigned long long* __restrict__ slotB,
                                                    float* __restrict__ out) {
    __shared__ float s_row[NB];
    __shared__ int   s_plist[64];
    __shared__ int   s_cnt;
    __shared__ float s_red[12];               // 6 waves x {sum,cnt}

    const int i = blockIdx.x;
    const int t = threadIdx.x;
    const int w = t >> 6;                     // wave 0..5
    const int l = t & 63;                     // lane

    if (t == 0) s_cnt = 0;

    // anchor fragment in registers: lane l owns dims 4l..4l+3 (L1-hot, uniform per wave)
    const float4 ea = ((const float4*)(emb + (size_t)i * ND))[l];

    // wave w computes d(i, j) for j = 64w .. 64w+63; row reads fully coalesced
    const int jbase = w << 6;
    #pragma unroll 4
    for (int jj = 0; jj < 64; ++jj) {
        const int j = jbase + jj;
        const float4 v = ((const float4*)(emb + (size_t)j * ND))[l];
        const float a0 = ea.x - v.x;
        const float a1 = ea.y - v.y;
        const float a2 = ea.z - v.z;
        const float a3 = ea.w - v.w;
        float p = a0 * a0;
        p = fmaf(a1, a1, p);
        p = fmaf(a2, a2, p);
        p = fmaf(a3, a3, p);
        #pragma unroll
        for (int off = 32; off; off >>= 1) p += __shfl_xor(p, off, 64);
        if (l == jj) s_row[j] = sqrtf(p);     // j==i gives exact 0
    }

    const int li = labels[i];                 // uniform
    const int lt = labels[t];                 // coalesced
    const bool neg = (lt != li);
    __syncthreads();                          // s_row + s_cnt visible

    if (!neg && t != i) {
        int p = atomicAdd(&s_cnt, 1);
        if (p < 64) s_plist[p] = t;
    }
    __syncthreads();                          // plist visible

    const float r1 = s_row[t];
    const int np = (s_cnt < 64) ? s_cnt : 64;
    float sum = 0.f, cnt = 0.f;
    if (neg) {
        for (int p = 0; p < np; ++p) {
            float v = s_row[s_plist[p]] + MARGIN - r1;
            if (v > 0.f)    sum += v;
            if (v > 1e-16f) cnt += 1.f;
        }
    }

    // block reduction: 6 waves
    #pragma unroll
    for (int off = 32; off; off >>= 1) {
        sum += __shfl_xor(sum, off, 64);
        cnt += __shfl_xor(cnt, off, 64);
    }
    if (l == 0) { s_red[w] = sum; s_red[6 + w] = cnt; }
    __syncthreads();

    if (t == 0) {
        float ts = 0.f, tc = 0.f;
        #pragma unroll
        for (int q = 0; q < 6; ++q) { ts += s_red[q]; tc += s_red[6 + q]; }
        unsigned long long a = ((unsigned long long)MAGIC_A << 32) |
                               (unsigned long long)__float_as_uint(ts);
        unsigned long long b = ((unsigned long long)MAGIC_B << 32) |
                               (unsigned long long)__float_as_uint(tc);
        __hip_atomic_store(&slotA[i], a, __ATOMIC_RELEASE, __HIP_MEMORY_SCOPE_AGENT);
        __hip_atomic_store(&slotB[i], b, __ATOMIC_RELEASE, __HIP_MEMORY_SCOPE_AGENT);
    }

    // block 0: collect all 384 partials, finalize, self-clean
    if (i == 0) {
        unsigned long long a, b;
        do {
            a = __hip_atomic_load(&slotA[t], __ATOMIC_ACQUIRE, __HIP_MEMORY_SCOPE_AGENT);
        } while ((unsigned)(a >> 32) != MAGIC_A);
        do {
            b = __hip_atomic_load(&slotB[t], __ATOMIC_ACQUIRE, __HIP_MEMORY_SCOPE_AGENT);
        } while ((unsigned)(b >> 32) != MAGIC_B);
        float fs = __uint_as_float((unsigned)(a & 0xFFFFFFFFu));
        float fc = __uint_as_float((unsigned)(b & 0xFFFFFFFFu));
        // reset so the next replay can't see stale magic
        __hip_atomic_store(&slotA[t], 0ull, __ATOMIC_RELAXED, __HIP_MEMORY_SCOPE_AGENT);
        __hip_atomic_store(&slotB[t], 0ull, __ATOMIC_RELAXED, __HIP_MEMORY_SCOPE_AGENT);

        __syncthreads();                      // s_red reuse
        #pragma unroll
        for (int off = 32; off; off >>= 1) {
            fs += __shfl_xor(fs, off, 64);
            fc += __shfl_xor(fc, off, 64);
        }
        if (l == 0) { s_red[w] = fs; s_red[6 + w] = fc; }
        __syncthreads();
        if (t == 0) {
            float ts = 0.f, tc = 0.f;
            #pragma unroll
            for (int q = 0; q < 6; ++q) { ts += s_red[q]; tc += s_red[6 + q]; }
            out[0] = ts / (tc + 1e-16f);
        }
    }
}

extern "C" void kernel_launch(void* const* d_in, const int* in_sizes, int n_in,
                              void* d_out, int out_size, void* d_ws, size_t ws_size,
                              hipStream_t stream) {
    const float* emb    = (const float*)d_in[0];
    const int*   labels = (const int*)d_in[1];
    float*       out    = (float*)d_out;

    unsigned long long* slotA = (unsigned long long*)d_ws;            // 384*8 B
    unsigned long long* slotB = slotA + NB;                           // 384*8 B

    fused_kernel<<<NB, NB, 0, stream>>>(emb, labels, slotA, slotB, out);
}

// Round 6
// 21.982 us; speedup vs baseline: 4.9178x; 1.7464x over previous
//
#include <hip/hip_runtime.h>
#include <math.h>

#define MARGIN 5.0f
#define NB 384
#define ND 256
#define NBLK 192
#define APB 2                 // anchors per block
#define DC 32                 // dims per chunk
#define NCH (ND / DC)         // 8 chunks
#define RP 33                 // s_tile row pitch (floats): (t+d)%32 -> 2-way, free
#define MAGIC_A 0x51B7A5E1u
#define MAGIC_B 0xC3D2E1F0u

// One plain kernel. Each block owns 2 anchors: stages emb through LDS in
// d-chunks (coalesced global reads, conflict-free LDS), accumulates both
// anchors' squared distances per thread (thread t = column j = t), does the
// masked triplet reduction, publishes {sum,cnt} with magic-tagged stores;
// block 0 spin-collects, finalizes, and resets slots (self-cleaning).
__global__ __launch_bounds__(384) void fused_kernel(const float* __restrict__ emb,
                                                    const int* __restrict__ labels,
                                                    unsigned long long* __restrict__ slotA,
                                                    unsigned long long* __restrict__ slotB,
                                                    float* __restrict__ out) {
    __shared__ float s_tile[NB][RP];      // 50688 B
    __shared__ float s_ea[APB][ND];       // 2048 B
    __shared__ float s_rowd[APB][NB];     // 3072 B
    __shared__ int   s_plist[64];
    __shared__ int   s_cnt;
    __shared__ float s_red[12];

    const int i0 = blockIdx.x * APB;
    const int t  = threadIdx.x;
    const int w  = t >> 6;                // wave 0..5
    const int l  = t & 63;                // lane

    // stage the 2 anchor rows into LDS (broadcast source for the FMA loop)
    for (int x = t; x < APB * ND; x += 384)
        s_ea[x >> 8][x & (ND - 1)] = emb[(size_t)(i0 + (x >> 8)) * ND + (x & (ND - 1))];

    // distance phase: chunked LDS staging + per-thread scalar accumulation
    float acc0 = 0.f, acc1 = 0.f;
    const int rbase = (w << 6) + (l >> 3);   // wave covers rows [w*64, w*64+64)
    const int dq    = (l & 7) << 2;          // float offset within chunk (float4)

    for (int c = 0; c < NCH; ++c) {
        __syncthreads();                  // prev chunk consumed (covers s_ea on c=0)
        #pragma unroll
        for (int q = 0; q < 8; ++q) {
            const int r = rbase + (q << 3);
            const float4 v = *(const float4*)(emb + (size_t)r * ND + c * DC + dq);
            s_tile[r][dq]     = v.x;      // scalar writes: 2-way banks, free
            s_tile[r][dq + 1] = v.y;
            s_tile[r][dq + 2] = v.z;
            s_tile[r][dq + 3] = v.w;
        }
        __syncthreads();
        #pragma unroll
        for (int d = 0; d < DC; ++d) {
            const float ev = s_tile[t][d];            // 2-way banks, free
            const float d0 = s_ea[0][c * DC + d] - ev; // LDS broadcast
            const float d1 = s_ea[1][c * DC + d] - ev;
            acc0 = fmaf(d0, d0, acc0);
            acc1 = fmaf(d1, d1, acc1);
        }
    }
    s_rowd[0][t] = sqrtf(acc0);           // j==i gives exact 0
    s_rowd[1][t] = sqrtf(acc1);

    // triplet phase, per anchor
    const int lt = labels[t];             // coalesced, load once
    float sum = 0.f, cnt = 0.f;
    for (int a = 0; a < APB; ++a) {
        const int i  = i0 + a;
        const int li = labels[i];         // uniform
        __syncthreads();                  // s_rowd ready / prev plist consumed
        if (t == 0) s_cnt = 0;
        __syncthreads();
        if (lt == li && t != i) {
            int p = atomicAdd(&s_cnt, 1);
            if (p < 64) s_plist[p] = t;
        }
        __syncthreads();
        const int np = (s_cnt < 64) ? s_cnt : 64;
        if (lt != li) {
            const float r1 = s_rowd[a][t];
            for (int p = 0; p < np; ++p) {
                float v = s_rowd[a][s_plist[p]] + MARGIN - r1;  // LDS broadcast
                if (v > 0.f)    sum += v;
                if (v > 1e-16f) cnt += 1.f;
            }
        }
    }

    // block reduction: 6 waves
    #pragma unroll
    for (int off = 32; off; off >>= 1) {
        sum += __shfl_xor(sum, off, 64);
        cnt += __shfl_xor(cnt, off, 64);
    }
    if (l == 0) { s_red[w] = sum; s_red[6 + w] = cnt; }
    __syncthreads();

    if (t == 0) {
        float ts = 0.f, tc = 0.f;
        #pragma unroll
        for (int q = 0; q < 6; ++q) { ts += s_red[q]; tc += s_red[6 + q]; }
        unsigned long long a = ((unsigned long long)MAGIC_A << 32) |
                               (unsigned long long)__float_as_uint(ts);
        unsigned long long b = ((unsigned long long)MAGIC_B << 32) |
                               (unsigned long long)__float_as_uint(tc);
        __hip_atomic_store(&slotA[blockIdx.x], a, __ATOMIC_RELEASE, __HIP_MEMORY_SCOPE_AGENT);
        __hip_atomic_store(&slotB[blockIdx.x], b, __ATOMIC_RELEASE, __HIP_MEMORY_SCOPE_AGENT);
    }

    // block 0: collect 192 partials (payload lives inside the atomic word),
    // finalize, self-clean
    if (blockIdx.x == 0) {
        float fs = 0.f, fc = 0.f;
        if (t < NBLK) {
            unsigned long long a, b;
            do {
                a = __hip_atomic_load(&slotA[t], __ATOMIC_ACQUIRE, __HIP_MEMORY_SCOPE_AGENT);
            } while ((unsigned)(a >> 32) != MAGIC_A);
            do {
                b = __hip_atomic_load(&slotB[t], __ATOMIC_ACQUIRE, __HIP_MEMORY_SCOPE_AGENT);
            } while ((unsigned)(b >> 32) != MAGIC_B);
            fs = __uint_as_float((unsigned)(a & 0xFFFFFFFFu));
            fc = __uint_as_float((unsigned)(b & 0xFFFFFFFFu));
            __hip_atomic_store(&slotA[t], 0ull, __ATOMIC_RELAXED, __HIP_MEMORY_SCOPE_AGENT);
            __hip_atomic_store(&slotB[t], 0ull, __ATOMIC_RELAXED, __HIP_MEMORY_SCOPE_AGENT);
        }
        __syncthreads();                  // s_red reuse
        #pragma unroll
        for (int off = 32; off; off >>= 1) {
            fs += __shfl_xor(fs, off, 64);
            fc += __shfl_xor(fc, off, 64);
        }
        if (l == 0) { s_red[w] = fs; s_red[6 + w] = fc; }
        __syncthreads();
        if (t == 0) {
            float ts = 0.f, tc = 0.f;
            #pragma unroll
            for (int q = 0; q < 6; ++q) { ts += s_red[q]; tc += s_red[6 + q]; }
            out[0] = ts / (tc + 1e-16f);
        }
    }
}

extern "C" void kernel_launch(void* const* d_in, const int* in_sizes, int n_in,
                              void* d_out, int out_size, void* d_ws, size_t ws_size,
                              hipStream_t stream) {
    const float* emb    = (const float*)d_in[0];
    const int*   labels = (const int*)d_in[1];
    float*       out    = (float*)d_out;

    unsigned long long* slotA = (unsigned long long*)d_ws;   // 192*8 B
    unsigned long long* slotB = slotA + NBLK;                // 192*8 B

    fused_kernel<<<NBLK, NB, 0, stream>>>(emb, labels, slotA, slotB, out);
}

// Round 7
// 20.297 us; speedup vs baseline: 5.3261x; 1.0830x over previous
//
#include <hip/hip_runtime.h>
#include <math.h>

#define MARGIN 5.0f
#define NB 384
#define ND 256
#define NBLK 192
#define APB 2                 // anchors per block
#define DC 32                 // dims per chunk
#define NCH 8                 // chunks
#define NQ 8                  // float4 per row-chunk
#define MAGIC_A 0x51B7A5E1u
#define MAGIC_B 0xC3D2E1F0u

// async global->LDS, 16B per lane; LDS dest = wave-uniform base + lane*16
__device__ __forceinline__ void gload_lds16(const float* g, void* l) {
    __builtin_amdgcn_global_load_lds((const __attribute__((address_space(1))) void*)g,
                                     (__attribute__((address_space(3))) void*)l, 16, 0, 0);
}

// One plain kernel, 192 blocks x 384 threads, 2 anchors/block.
// Distance phase: double-buffered global_load_lds staging of emb in d-chunks
// with XOR-swizzled layout (qslot = r*8 + (d4 ^ (r&7))); thread t reads its own
// row via conflict-free ds_read_b128; anchors come via wave-uniform s_loads.
// Publish {sum,cnt} with magic-tagged slots; block 0 spin-collects (poison-robust),
// finalizes, resets slots.
__global__ __launch_bounds__(384) void fused_kernel(const float* __restrict__ emb,
                                                    const int* __restrict__ labels,
                                                    unsigned long long* __restrict__ slotA,
                                                    unsigned long long* __restrict__ slotB,
                                                    float* __restrict__ out) {
    __shared__ float4 s_tile[2][NB * NQ];   // 2 x 48 KB
    __shared__ float  s_rowd[APB][NB];
    __shared__ int    s_plist[APB][64];
    __shared__ int    s_cnt[APB];
    __shared__ float  s_red[12];

    const int i0 = blockIdx.x * APB;
    const int t  = threadIdx.x;
    const int w  = t >> 6;                  // wave 0..5
    const int l  = t & 63;                  // lane

    const int lt = labels[t];               // issue early; drained by first vmcnt

    // per-lane pre-swizzled global source:
    // LDS qslot s = (w*8+q)*64 + l  ->  row r = w*64 + q*8 + (l>>3), d4 = (l&7)^(l>>3)
    const float* gsrc0 = emb + (size_t)(w * 64 + (l >> 3)) * ND + 4 * ((l & 7) ^ (l >> 3));

    const float* ea0 = emb + (size_t)(i0 + 0) * ND;   // uniform -> s_load
    const float* ea1 = emb + (size_t)(i0 + 1) * ND;

    float acc0 = 0.f, acc1 = 0.f;
    const int xk = t & 7;
    const int tq = t * NQ;

    // prologue: chunk 0 -> buf 0
    #pragma unroll
    for (int q = 0; q < NQ; ++q)
        gload_lds16(gsrc0 + (size_t)q * 8 * ND, &s_tile[0][(w * NQ + q) * 64]);

    #pragma unroll
    for (int c = 0; c < NCH; ++c) {
        const int b = c & 1;
        if (c + 1 < NCH) {
            #pragma unroll
            for (int q = 0; q < NQ; ++q)
                gload_lds16(gsrc0 + (size_t)q * 8 * ND + (c + 1) * DC,
                            &s_tile[b ^ 1][(w * NQ + q) * 64]);
            asm volatile("s_waitcnt vmcnt(8)" ::: "memory");   // chunk c landed
        } else {
            asm volatile("s_waitcnt vmcnt(0)" ::: "memory");
        }
        __builtin_amdgcn_s_barrier();                          // tile c visible to all
        asm volatile("" ::: "memory");

        #pragma unroll
        for (int d4 = 0; d4 < NQ; ++d4) {
            const float4 tv = s_tile[b][tq + (d4 ^ xk)];       // ds_read_b128, conflict-free
            const float4 e0 = *(const float4*)(ea0 + c * DC + 4 * d4);  // uniform s_load
            const float4 e1 = *(const float4*)(ea1 + c * DC + 4 * d4);
            float d;
            d = e0.x - tv.x; acc0 = fmaf(d, d, acc0);
            d = e0.y - tv.y; acc0 = fmaf(d, d, acc0);
            d = e0.z - tv.z; acc0 = fmaf(d, d, acc0);
            d = e0.w - tv.w; acc0 = fmaf(d, d, acc0);
            d = e1.x - tv.x; acc1 = fmaf(d, d, acc1);
            d = e1.y - tv.y; acc1 = fmaf(d, d, acc1);
            d = e1.z - tv.z; acc1 = fmaf(d, d, acc1);
            d = e1.w - tv.w; acc1 = fmaf(d, d, acc1);
        }
        asm volatile("s_waitcnt lgkmcnt(0)" ::: "memory");     // my reads of buf b done
        __builtin_amdgcn_s_barrier();                          // safe to overwrite buf b
        asm volatile("" ::: "memory");
    }

    // ---- triplet phase ----
    s_rowd[0][t] = sqrtf(acc0);             // t==i gives exact 0
    s_rowd[1][t] = sqrtf(acc1);
    if (t < APB) s_cnt[t] = 0;
    const int li0 = labels[i0];             // uniform
    const int li1 = labels[i0 + 1];
    __syncthreads();

    if (lt == li0 && t != i0)     { int p = atomicAdd(&s_cnt[0], 1); if (p < 64) s_plist[0][p] = t; }
    if (lt == li1 && t != i0 + 1) { int p = atomicAdd(&s_cnt[1], 1); if (p < 64) s_plist[1][p] = t; }
    __syncthreads();

    float sum = 0.f, cnt = 0.f;
    #pragma unroll
    for (int a = 0; a < APB; ++a) {
        const int li = a ? li1 : li0;
        if (lt != li) {
            const float r1 = s_rowd[a][t];
            const int np = (s_cnt[a] < 64) ? s_cnt[a] : 64;
            for (int p = 0; p < np; ++p) {
                float v = s_rowd[a][s_plist[a][p]] + MARGIN - r1;
                if (v > 0.f)    sum += v;
                if (v > 1e-16f) cnt += 1.f;
            }
        }
    }

    // block reduction: 6 waves
    #pragma unroll
    for (int off = 32; off; off >>= 1) {
        sum += __shfl_xor(sum, off, 64);
        cnt += __shfl_xor(cnt, off, 64);
    }
    if (l == 0) { s_red[w] = sum; s_red[6 + w] = cnt; }
    __syncthreads();

    if (t == 0) {
        float ts = 0.f, tc = 0.f;
        #pragma unroll
        for (int q = 0; q < 6; ++q) { ts += s_red[q]; tc += s_red[6 + q]; }
        unsigned long long a = ((unsigned long long)MAGIC_A << 32) |
                               (unsigned long long)__float_as_uint(ts);
        unsigned long long b = ((unsigned long long)MAGIC_B << 32) |
                               (unsigned long long)__float_as_uint(tc);
        __hip_atomic_store(&slotA[blockIdx.x], a, __ATOMIC_RELEASE, __HIP_MEMORY_SCOPE_AGENT);
        __hip_atomic_store(&slotB[blockIdx.x], b, __ATOMIC_RELEASE, __HIP_MEMORY_SCOPE_AGENT);
    }

    // block 0: spin-collect 192 partials, finalize, self-clean
    if (blockIdx.x == 0) {
        float fs = 0.f, fc = 0.f;
        if (t < NBLK) {
            unsigned long long a = __hip_atomic_load(&slotA[t], __ATOMIC_ACQUIRE, __HIP_MEMORY_SCOPE_AGENT);
            while ((unsigned)(a >> 32) != MAGIC_A) {
                __builtin_amdgcn_s_sleep(2);
                a = __hip_atomic_load(&slotA[t], __ATOMIC_ACQUIRE, __HIP_MEMORY_SCOPE_AGENT);
            }
            unsigned long long b = __hip_atomic_load(&slotB[t], __ATOMIC_ACQUIRE, __HIP_MEMORY_SCOPE_AGENT);
            while ((unsigned)(b >> 32) != MAGIC_B) {
                __builtin_amdgcn_s_sleep(2);
                b = __hip_atomic_load(&slotB[t], __ATOMIC_ACQUIRE, __HIP_MEMORY_SCOPE_AGENT);
            }
            fs = __uint_as_float((unsigned)(a & 0xFFFFFFFFu));
            fc = __uint_as_float((unsigned)(b & 0xFFFFFFFFu));
            __hip_atomic_store(&slotA[t], 0ull, __ATOMIC_RELAXED, __HIP_MEMORY_SCOPE_AGENT);
            __hip_atomic_store(&slotB[t], 0ull, __ATOMIC_RELAXED, __HIP_MEMORY_SCOPE_AGENT);
        }
        __syncthreads();                    // s_red reuse
        #pragma unroll
        for (int off = 32; off; off >>= 1) {
            fs += __shfl_xor(fs, off, 64);
            fc += __shfl_xor(fc, off, 64);
        }
        if (l == 0) { s_red[w] = fs; s_red[6 + w] = fc; }
        __syncthreads();
        if (t == 0) {
            float ts = 0.f, tc = 0.f;
            #pragma unroll
            for (int q = 0; q < 6; ++q) { ts += s_red[q]; tc += s_red[6 + q]; }
            out[0] = ts / (tc + 1e-16f);
        }
    }
}

extern "C" void kernel_launch(void* const* d_in, const int* in_sizes, int n_in,
                              void* d_out, int out_size, void* d_ws, size_t ws_size,
                              hipStream_t stream) {
    const float* emb    = (const float*)d_in[0];
    const int*   labels = (const int*)d_in[1];
    float*       out    = (float*)d_out;

    unsigned long long* slotA = (unsigned long long*)d_ws;   // 192*8 B
    unsigned long long* slotB = slotA + NBLK;                // 192*8 B

    fused_kernel<<<NBLK, NB, 0, stream>>>(emb, labels, slotA, slotB, out);
}

// Round 8
// 20.049 us; speedup vs baseline: 5.3919x; 1.0123x over previous
//
#include <hip/hip_runtime.h>
#include <math.h>

#define MARGIN 5.0f
#define NB 384
#define ND 256
#define NBLK 192
#define APB 2                 // anchors per block
#define DC 32                 // dims per chunk
#define NCH 8                 // chunks
#define NQ 8                  // float4 per row-chunk
#define MAGIC_A 0x51B7A5E1u
#define MAGIC_B 0xC3D2E1F0u

// async global->LDS, 16B per lane; LDS dest = wave-uniform base + lane*16
__device__ __forceinline__ void gload_lds16(const float* g, void* l) {
    __builtin_amdgcn_global_load_lds((const __attribute__((address_space(1))) void*)g,
                                     (__attribute__((address_space(3))) void*)l, 16, 0, 0);
}

// One plain kernel, 192 blocks x 384 threads, 2 anchors/block.
// Distance phase: double-buffered global_load_lds staging with XOR-swizzled
// layout; tile regions are WAVE-PRIVATE (thread t reads only slots t*8..t*8+7,
// written by its own wave) -> NO barriers, only per-wave counted vmcnt.
// Publish {sum,cnt} via magic-tagged slots; block 0 spin-collects, finalizes,
// resets slots (self-cleaning, poison-robust).
__global__ __launch_bounds__(384) void fused_kernel(const float* __restrict__ emb,
                                                    const int* __restrict__ labels,
                                                    unsigned long long* __restrict__ slotA,
                                                    unsigned long long* __restrict__ slotB,
                                                    float* __restrict__ out) {
    __shared__ float4 s_tile[2][NB * NQ];   // 2 x 48 KB
    __shared__ float  s_rowd[APB][NB];
    __shared__ int    s_plist[APB][64];
    __shared__ int    s_cnt[APB];
    __shared__ float  s_red[12];

    const int i0 = blockIdx.x * APB;
    const int t  = threadIdx.x;
    const int w  = t >> 6;                  // wave 0..5
    const int l  = t & 63;                  // lane

    const int lt = labels[t];               // issue early; drained by first vmcnt
    if (t < APB) s_cnt[t] = 0;              // visible after the one __syncthreads

    // per-lane pre-swizzled global source:
    // LDS qslot s = (w*8+q)*64 + l  ->  row r = w*64 + q*8 + (l>>3), d4 = (l&7)^(l>>3)
    const float* gsrc0 = emb + (size_t)(w * 64 + (l >> 3)) * ND + 4 * ((l & 7) ^ (l >> 3));

    const float* ea0 = emb + (size_t)(i0 + 0) * ND;   // uniform -> s_load
    const float* ea1 = emb + (size_t)(i0 + 1) * ND;

    float acc0 = 0.f, acc1 = 0.f;
    const int xk = t & 7;
    const int tq = t * NQ;

    // prologue: chunk 0 -> buf 0
    #pragma unroll
    for (int q = 0; q < NQ; ++q)
        gload_lds16(gsrc0 + (size_t)q * 8 * ND, &s_tile[0][(w * NQ + q) * 64]);

    #pragma unroll
    for (int c = 0; c < NCH; ++c) {
        const int b = c & 1;
        if (c + 1 < NCH) {
            #pragma unroll
            for (int q = 0; q < NQ; ++q)
                gload_lds16(gsrc0 + (size_t)q * 8 * ND + (c + 1) * DC,
                            &s_tile[b ^ 1][(w * NQ + q) * 64]);
            asm volatile("s_waitcnt vmcnt(8)" ::: "memory");   // my chunk c landed
        } else {
            asm volatile("s_waitcnt vmcnt(0)" ::: "memory");
        }
        // no barrier: buf region [t*8, t*8+8) is written by this wave only

        #pragma unroll
        for (int d4 = 0; d4 < NQ; ++d4) {
            const float4 tv = s_tile[b][tq + (d4 ^ xk)];       // ds_read_b128, conflict-free
            const float4 e0 = *(const float4*)(ea0 + c * DC + 4 * d4);  // uniform s_load
            const float4 e1 = *(const float4*)(ea1 + c * DC + 4 * d4);
            float d;
            d = e0.x - tv.x; acc0 = fmaf(d, d, acc0);
            d = e0.y - tv.y; acc0 = fmaf(d, d, acc0);
            d = e0.z - tv.z; acc0 = fmaf(d, d, acc0);
            d = e0.w - tv.w; acc0 = fmaf(d, d, acc0);
            d = e1.x - tv.x; acc1 = fmaf(d, d, acc1);
            d = e1.y - tv.y; acc1 = fmaf(d, d, acc1);
            d = e1.z - tv.z; acc1 = fmaf(d, d, acc1);
            d = e1.w - tv.w; acc1 = fmaf(d, d, acc1);
        }
        // WAR on buf b^1 is safe: compiler drains lgkmcnt before FMA-use, which
        // precedes next iteration's stage-issue in program order
    }

    // ---- triplet phase ----
    s_rowd[0][t] = sqrtf(acc0);             // t==i gives exact 0
    s_rowd[1][t] = sqrtf(acc1);
    const int li0 = labels[i0];             // uniform
    const int li1 = labels[i0 + 1];
    __syncthreads();                        // s_rowd + s_cnt init visible

    if (lt == li0 && t != i0)     { int p = atomicAdd(&s_cnt[0], 1); if (p < 64) s_plist[0][p] = t; }
    if (lt == li1 && t != i0 + 1) { int p = atomicAdd(&s_cnt[1], 1); if (p < 64) s_plist[1][p] = t; }
    __syncthreads();

    float sum = 0.f, cnt = 0.f;
    #pragma unroll
    for (int a = 0; a < APB; ++a) {
        const int li = a ? li1 : li0;
        if (lt != li) {
            const float r1 = s_rowd[a][t];
            const int np = (s_cnt[a] < 64) ? s_cnt[a] : 64;
            for (int p = 0; p < np; ++p) {
                float v = s_rowd[a][s_plist[a][p]] + MARGIN - r1;
                if (v > 0.f)    sum += v;
                if (v > 1e-16f) cnt += 1.f;
            }
        }
    }

    // block reduction: 6 waves
    #pragma unroll
    for (int off = 32; off; off >>= 1) {
        sum += __shfl_xor(sum, off, 64);
        cnt += __shfl_xor(cnt, off, 64);
    }
    if (l == 0) { s_red[w] = sum; s_red[6 + w] = cnt; }
    __syncthreads();

    if (t == 0) {
        float ts = 0.f, tc = 0.f;
        #pragma unroll
        for (int q = 0; q < 6; ++q) { ts += s_red[q]; tc += s_red[6 + q]; }
        unsigned long long a = ((unsigned long long)MAGIC_A << 32) |
                               (unsigned long long)__float_as_uint(ts);
        unsigned long long b = ((unsigned long long)MAGIC_B << 32) |
                               (unsigned long long)__float_as_uint(tc);
        __hip_atomic_store(&slotA[blockIdx.x], a, __ATOMIC_RELEASE, __HIP_MEMORY_SCOPE_AGENT);
        __hip_atomic_store(&slotB[blockIdx.x], b, __ATOMIC_RELEASE, __HIP_MEMORY_SCOPE_AGENT);
    }

    // block 0: spin-collect 192 partials, finalize, self-clean
    if (blockIdx.x == 0) {
        float fs = 0.f, fc = 0.f;
        if (t < NBLK) {
            unsigned long long a = __hip_atomic_load(&slotA[t], __ATOMIC_ACQUIRE, __HIP_MEMORY_SCOPE_AGENT);
            while ((unsigned)(a >> 32) != MAGIC_A) {
                __builtin_amdgcn_s_sleep(2);
                a = __hip_atomic_load(&slotA[t], __ATOMIC_ACQUIRE, __HIP_MEMORY_SCOPE_AGENT);
            }
            unsigned long long b = __hip_atomic_load(&slotB[t], __ATOMIC_ACQUIRE, __HIP_MEMORY_SCOPE_AGENT);
            while ((unsigned)(b >> 32) != MAGIC_B) {
                __builtin_amdgcn_s_sleep(2);
                b = __hip_atomic_load(&slotB[t], __ATOMIC_ACQUIRE, __HIP_MEMORY_SCOPE_AGENT);
            }
            fs = __uint_as_float((unsigned)(a & 0xFFFFFFFFu));
            fc = __uint_as_float((unsigned)(b & 0xFFFFFFFFu));
            __hip_atomic_store(&slotA[t], 0ull, __ATOMIC_RELAXED, __HIP_MEMORY_SCOPE_AGENT);
            __hip_atomic_store(&slotB[t], 0ull, __ATOMIC_RELAXED, __HIP_MEMORY_SCOPE_AGENT);
        }
        __syncthreads();                    // s_red reuse
        #pragma unroll
        for (int off = 32; off; off >>= 1) {
            fs += __shfl_xor(fs, off, 64);
            fc += __shfl_xor(fc, off, 64);
        }
        if (l == 0) { s_red[w] = fs; s_red[6 + w] = fc; }
        __syncthreads();
        if (t == 0) {
            float ts = 0.f, tc = 0.f;
            #pragma unroll
            for (int q = 0; q < 6; ++q) { ts += s_red[q]; tc += s_red[6 + q]; }
            out[0] = ts / (tc + 1e-16f);
        }
    }
}

extern "C" void kernel_launch(void* const* d_in, const int* in_sizes, int n_in,
                              void* d_out, int out_size, void* d_ws, size_t ws_size,
                              hipStream_t stream) {
    const float* emb    = (const float*)d_in[0];
    const int*   labels = (const int*)d_in[1];
    float*       out    = (float*)d_out;

    unsigned long long* slotA = (unsigned long long*)d_ws;   // 192*8 B
    unsigned long long* slotB = slotA + NBLK;                // 192*8 B

    fused_kernel<<<NBLK, NB, 0, stream>>>(emb, labels, slotA, slotB, out);
}